// Round 3
// baseline (1060.638 us; speedup 1.0000x reference)
//
#include <hip/hip_runtime.h>

// SAXS loss: soft-binned pair-distance histograms for pred & true structures,
// normalized, then L1-summed. N = 256*37 = 9472 atoms = 37 tiles of 256 exactly.
// Symmetry: count i<j only (doubling cancels in normalization).
//
// R3: atomicAdd(float) on AMD lowers to a CAS retry loop unless unsafe-fp-
// atomics is enabled -> measured 215 cyc per LDS atomic instr in R2. Switch
// to unsafeAtomicAdd (native ds_add_f32 / global_atomic_add_f32, no return,
// no wait). Also 32 LDS replicas (2 lanes each) and skip w==0 atomics.

#define NATOMS  9472
#define TILE    256
#define NTILES  37                            // 9472 / 256, exact
#define TPAIRS  (NTILES * (NTILES + 1) / 2)   // 703 triangular tile pairs
#define NBINS   201
#define NREP    32                            // LDS histogram replicas
#define HSTRIDE 256                           // per-structure hist stride in ws

__global__ __launch_bounds__(TILE) void saxs_hist_kernel(
    const float* __restrict__ posPred,
    const float* __restrict__ posTrue,
    const float* __restrict__ mask,
    float* __restrict__ gh)
{
    const int t    = threadIdx.x;
    const int lane = t & 63;
    const int s    = blockIdx.y;               // 0 = pred, 1 = true
    const float* __restrict__ pos = s ? posTrue : posPred;
    float* __restrict__ ghist = gh + s * HSTRIDE;

    // Decode triangular tile index -> (a, b), a <= b. Wave-uniform, once.
    int p = blockIdx.x;
    int a = 0;
    while (p >= NTILES - a) { p -= NTILES - a; ++a; }
    const int b = a + p;

    __shared__ float sHist[NREP * NBINS];      // stride 201: gcd(201,32)=1 ->
                                               // one bin's replicas span all banks

    for (int k = t; k < NREP * NBINS; k += TILE) sHist[k] = 0.0f;

    // j-atom (one per thread) from tile b.
    const int jg = b * TILE + t;
    const float xj = pos[3 * jg], yj = pos[3 * jg + 1], zj = pos[3 * jg + 2];
    const float mj = mask[jg];

    __syncthreads();

    float* __restrict__ rep = sHist + (t & (NREP - 1)) * NBINS;

    // i-tile (tile a, 256 atoms) in 4 chunks of 64: one atom per lane in
    // registers, broadcast with readlane (VALU pipe, no LDS reads).
    for (int c = 0; c < 4; ++c) {
        const int ia = a * TILE + c * 64 + lane;
        const int cx = __float_as_int(pos[3 * ia]);
        const int cy = __float_as_int(pos[3 * ia + 1]);
        const int cz = __float_as_int(pos[3 * ia + 2]);
        const int cm = __float_as_int(mask[ia]);

        #pragma unroll
        for (int i = 0; i < 64; ++i) {
            const float sx = __int_as_float(__builtin_amdgcn_readlane(cx, i));
            const float sy = __int_as_float(__builtin_amdgcn_readlane(cy, i));
            const float sz = __int_as_float(__builtin_amdgcn_readlane(cz, i));
            const float sm = __int_as_float(__builtin_amdgcn_readlane(cm, i));
            const int   ig = a * TILE + c * 64 + i;

            const float dx = sx - xj;
            const float dy = sy - yj;
            const float dz = sz - zj;
            const float d2 = fmaf(dx, dx, fmaf(dy, dy, dz * dz));
            const float d  = sqrtf(fmaxf(d2, 1e-12f));
            // clip(d/0.5, 0, NBINS-1.000001): fp32 upper bound is exactly 200.0f
            const float tt = fminf(d * 2.0f, 200.0f);
            const float fl = floorf(tt);
            const int   lo = (int)fl;
            const float frac = tt - fl;
            // i<j predicate folds diagonal masking + self-pair exclusion.
            const float w  = (ig < jg) ? sm * mj : 0.0f;
            if (w != 0.0f) {
                const float wf = w * frac;
                const float wl = w - wf;       // w*(1-frac)
                const int   hi = lo < (NBINS - 1) ? lo + 1 : (NBINS - 1);
                unsafeAtomicAdd(&rep[lo], wl); // native ds_add_f32, no return
                unsafeAtomicAdd(&rep[hi], wf);
            }
        }
    }

    __syncthreads();

    // Reduce replicas, one global atomic per bin per block.
    for (int k = t; k < NBINS; k += TILE) {
        float acc = 0.0f;
        #pragma unroll
        for (int r = 0; r < NREP; ++r) acc += sHist[r * NBINS + k];
        unsafeAtomicAdd(&ghist[k], acc);       // native global_atomic_add_f32
    }
}

__global__ void saxs_loss_kernel(const float* __restrict__ gh, float* __restrict__ out)
{
    const int lane = threadIdx.x;              // single wave of 64
    float hp[4], ht[4];
    float sp = 0.0f, st = 0.0f;
    #pragma unroll
    for (int r = 0; r < 4; ++r) {
        const int k = lane + 64 * r;
        float a = 0.0f, c = 0.0f;
        if (k < NBINS) { a = gh[k]; c = gh[HSTRIDE + k]; }
        hp[r] = a; ht[r] = c;
        sp += a; st += c;
    }
    #pragma unroll
    for (int off = 32; off > 0; off >>= 1) {
        sp += __shfl_xor(sp, off);
        st += __shfl_xor(st, off);
    }
    sp += 1e-12f;
    st += 1e-12f;
    float l = 0.0f;
    #pragma unroll
    for (int r = 0; r < 4; ++r) l += fabsf(hp[r] / sp - ht[r] / st);
    #pragma unroll
    for (int off = 32; off > 0; off >>= 1) l += __shfl_xor(l, off);
    if (lane == 0) out[0] = l;
}

extern "C" void kernel_launch(void* const* d_in, const int* in_sizes, int n_in,
                              void* d_out, int out_size, void* d_ws, size_t ws_size,
                              hipStream_t stream)
{
    const float* pred = (const float*)d_in[0];  // final_atom_positions [256,37,3]
    const float* tru  = (const float*)d_in[1];  // all_atom_positions   [256,37,3]
    const float* msk  = (const float*)d_in[2];  // all_atom_mask        [256,37]
    float* out = (float*)d_out;
    float* ws  = (float*)d_ws;

    // ws is poisoned 0xAA before every timed launch — zero the histograms.
    hipMemsetAsync(d_ws, 0, 2 * HSTRIDE * sizeof(float), stream);

    dim3 grid(TPAIRS, 2);
    saxs_hist_kernel<<<grid, dim3(TILE), 0, stream>>>(pred, tru, msk, ws);
    saxs_loss_kernel<<<dim3(1), dim3(64), 0, stream>>>(ws, out);
}

// Round 4
// 172.984 us; speedup vs baseline: 6.1314x; 6.1314x over previous
//
#include <hip/hip_runtime.h>

// SAXS loss: soft-binned pair-distance histograms for pred & true structures,
// normalized, then L1-summed. N = 256*37 = 9472 atoms = 37 tiles of 256 exactly.
// Symmetry: count i<j only (doubling cancels in normalization).
//
// R4: all-INTEGER accumulation. FP LDS atomics (R1-R3) cost ~215 cyc/instr
// (CAS slow path) regardless of atomicAdd vs unsafeAtomicAdd. Replace with
// q15 fixed point + ONE native ds_add_u64 per pair: low word -> bin lo,
// high word -> bin lo+1, via even/odd dual arrays so the 8B slot is aligned.
// Global accumulation = native global_atomic_add_x2 (u64, deterministic).

#define NATOMS  9472
#define TILE    256
#define NTILES  37                            // 9472 / 256, exact
#define TPAIRS  (NTILES * (NTILES + 1) / 2)   // 703 triangular tile pairs
#define NBINS   201
#define NREP    16                            // LDS histogram replicas
#define RSTRIDE 402                           // u32 words per replica: E=202, O=200
#define HSTRIDE 256                           // per-structure u64 hist stride in ws
#define QSCALE  32768.0f                      // q15

__global__ __launch_bounds__(TILE) void saxs_hist_kernel(
    const float* __restrict__ posPred,
    const float* __restrict__ posTrue,
    const float* __restrict__ mask,
    unsigned long long* __restrict__ gh)
{
    const int t    = threadIdx.x;
    const int lane = t & 63;
    const int s    = blockIdx.y;               // 0 = pred, 1 = true
    const float* __restrict__ pos = s ? posTrue : posPred;
    unsigned long long* __restrict__ ghist = gh + s * HSTRIDE;

    // Decode triangular tile index -> (a, b), a <= b. Wave-uniform, once.
    int p = blockIdx.x;
    int a = 0;
    while (p >= NTILES - a) { p -= NTILES - a; ++a; }
    const int b = a + p;

    // Per-replica layout (u32 view), replica r at r*RSTRIDE:
    //   E32[i] = base + i        (i in 0..201): contributes to bin i
    //   O32[j] = base + 202 + j  (j in 0..199): contributes to bin j+1
    // u64 slot for pair (lo, lo+1): u32 idx = base + (lo & ~1) + (lo&1 ? 202 : 0)
    // (always 8B-aligned since lo&~1 and 202 are even).
    __shared__ unsigned long long sHist64[NREP * RSTRIDE / 2];
    unsigned int* sHist = (unsigned int*)sHist64;

    for (int k = t; k < NREP * RSTRIDE; k += TILE) sHist[k] = 0u;

    // j-atom (one per thread) from tile b.
    const int jg = b * TILE + t;
    const float xj = pos[3 * jg], yj = pos[3 * jg + 1], zj = pos[3 * jg + 2];
    const float mj = mask[jg];

    __syncthreads();

    const int repBase = (t & (NREP - 1)) * RSTRIDE;

    // i-tile (tile a, 256 atoms) in 4 chunks of 64: one atom per lane in
    // registers, broadcast with readlane (VALU pipe, no LDS reads).
    for (int c = 0; c < 4; ++c) {
        const int ia = a * TILE + c * 64 + lane;
        const int cx = __float_as_int(pos[3 * ia]);
        const int cy = __float_as_int(pos[3 * ia + 1]);
        const int cz = __float_as_int(pos[3 * ia + 2]);
        const int cm = __float_as_int(mask[ia]);

        #pragma unroll
        for (int i = 0; i < 64; ++i) {
            const float sx = __int_as_float(__builtin_amdgcn_readlane(cx, i));
            const float sy = __int_as_float(__builtin_amdgcn_readlane(cy, i));
            const float sz = __int_as_float(__builtin_amdgcn_readlane(cz, i));
            const float sm = __int_as_float(__builtin_amdgcn_readlane(cm, i));
            const int   ig = a * TILE + c * 64 + i;

            const float dx = sx - xj;
            const float dy = sy - yj;
            const float dz = sz - zj;
            const float d2 = fmaf(dx, dx, fmaf(dy, dy, dz * dz));
            const float d  = sqrtf(fmaxf(d2, 1e-12f));
            // clip(d/0.5, 0, NBINS-1.000001): fp32 upper bound is exactly 200.0f
            const float tt = fminf(d * 2.0f, 200.0f);
            const float fl = floorf(tt);
            const int   lo = (int)fl;
            const float frac = tt - fl;        // == 0 whenever lo == 200
            // i<j predicate folds diagonal masking + self-pair exclusion.
            const float w  = (ig < jg) ? sm * mj : 0.0f;
            if (w != 0.0f) {
                const float    wp = w * QSCALE;
                const float    qf = wp * frac;
                const unsigned q  = __float2uint_rn(qf);       // -> bin lo+1
                const unsigned pq = __float2uint_rn(wp - qf);  // -> bin lo
                const unsigned long long pack =
                    ((unsigned long long)q << 32) | (unsigned long long)pq;
                const int idx32 = repBase + (lo & ~1) + ((lo & 1) ? 202 : 0);
                atomicAdd((unsigned long long*)&sHist[idx32], pack); // ds_add_u64
            }
        }
    }

    __syncthreads();

    // Reduce replicas; per block per bin fits u32 (<= 65536 pairs * 2^15 = 2^31).
    // One native u64 global atomic per bin per block.
    for (int k = t; k < NBINS; k += TILE) {
        unsigned int acc = 0;
        #pragma unroll
        for (int r = 0; r < NREP; ++r) {
            acc += sHist[r * RSTRIDE + k];                    // E32[k] -> bin k
            if (k > 0) acc += sHist[r * RSTRIDE + 202 + k - 1]; // O32[k-1] -> bin k
        }
        atomicAdd(&ghist[k], (unsigned long long)acc);        // global_atomic_add_x2
    }
}

__global__ void saxs_loss_kernel(const unsigned long long* __restrict__ gh,
                                 float* __restrict__ out)
{
    const int lane = threadIdx.x;              // single wave of 64
    float hp[4], ht[4];
    float sp = 0.0f, st = 0.0f;
    #pragma unroll
    for (int r = 0; r < 4; ++r) {
        const int k = lane + 64 * r;
        float a = 0.0f, c = 0.0f;
        if (k < NBINS) {
            a = (float)gh[k];
            c = (float)gh[HSTRIDE + k];
        }
        hp[r] = a; ht[r] = c;
        sp += a; st += c;
    }
    #pragma unroll
    for (int off = 32; off > 0; off >>= 1) {
        sp += __shfl_xor(sp, off);
        st += __shfl_xor(st, off);
    }
    sp += 1e-12f;
    st += 1e-12f;
    float l = 0.0f;
    #pragma unroll
    for (int r = 0; r < 4; ++r) l += fabsf(hp[r] / sp - ht[r] / st);
    #pragma unroll
    for (int off = 32; off > 0; off >>= 1) l += __shfl_xor(l, off);
    if (lane == 0) out[0] = l;
}

extern "C" void kernel_launch(void* const* d_in, const int* in_sizes, int n_in,
                              void* d_out, int out_size, void* d_ws, size_t ws_size,
                              hipStream_t stream)
{
    const float* pred = (const float*)d_in[0];  // final_atom_positions [256,37,3]
    const float* tru  = (const float*)d_in[1];  // all_atom_positions   [256,37,3]
    const float* msk  = (const float*)d_in[2];  // all_atom_mask        [256,37]
    float* out = (float*)d_out;
    unsigned long long* ws = (unsigned long long*)d_ws;

    // ws is poisoned 0xAA before every timed launch — zero the histograms.
    hipMemsetAsync(d_ws, 0, 2 * HSTRIDE * sizeof(unsigned long long), stream);

    dim3 grid(TPAIRS, 2);
    saxs_hist_kernel<<<grid, dim3(TILE), 0, stream>>>(pred, tru, msk, ws);
    saxs_loss_kernel<<<dim3(1), dim3(64), 0, stream>>>(ws, out);
}

// Round 5
// 147.846 us; speedup vs baseline: 7.1739x; 1.1700x over previous
//
#include <hip/hip_runtime.h>

// SAXS loss: soft-binned pair-distance histograms for pred & true structures,
// normalized, then L1-summed. N = 256*37 = 9472 atoms = 37 tiles of 256 exactly.
// Symmetry: count i<j only (doubling cancels in normalization).
//
// R4 -> R5: kernel was VALU-issue-bound at ~100 instr/pair. Cut to ~25:
// raw v_sqrt_f32 on pre-scaled (x2) coords, v_fract_f32, trunc cvts with
// fused +0.5 rounding, branch-free off-diagonal specialization, mad24
// addressing, dynamic-lane readlane (no 64x unroll -> fits I$), and
// NREP 16->32 (2 lanes/replica) to halve same-address LDS-atomic collisions.
// Accumulation stays all-integer: one native ds_add_u64 per pair packs the
// two adjacent-bin q15 contributions (low word -> bin lo, high -> lo+1).

#define TILE    256
#define NTILES  37                            // 9472 / 256, exact
#define TPAIRS  (NTILES * (NTILES + 1) / 2)   // 703 triangular tile pairs
#define NBINS   201
#define NREP    32                            // LDS histogram replicas
#define RSTRIDE 402                           // u32 words/replica: E=202, O=200
#define HSTRIDE 256                           // per-structure u64 hist stride in ws
#define QSCALE  32768.0f                      // q15

// Per-replica u32 layout at base r*RSTRIDE:
//   E[i] = base + i        (i 0..201): contributes to bin i   (E[201] dummy)
//   O[j] = base + 202 + j  (j 0..199): contributes to bin j+1
// u64 slot for (lo, lo+1): word idx = lo + 201*(lo&1)  — always even (aligned):
//   even lo -> words (lo, lo+1) = E[lo], E[lo+1]
//   odd  lo -> words (lo+201, lo+202) = O[lo-1], O[lo]
// Reduce: bin k = E[k] + (k>0 ? O[k-1] : 0).

template<bool DIAG>
__device__ __forceinline__ void accum_tile(
    const float* __restrict__ pos, const float* __restrict__ mask,
    int aBase, int t, int lane,
    float xj, float yj, float zj, float mjq,
    unsigned int* __restrict__ rep)
{
    #pragma unroll
    for (int c = 0; c < 4; ++c) {
        const int ia = aBase + c * 64 + lane;
        const int cx = __float_as_int(2.0f * pos[3 * ia]);
        const int cy = __float_as_int(2.0f * pos[3 * ia + 1]);
        const int cz = __float_as_int(2.0f * pos[3 * ia + 2]);
        const int cm = __float_as_int(mask[ia]);

        #pragma unroll 4
        for (int i = 0; i < 64; ++i) {         // dynamic-lane readlane: no 64x code
            const float sx = __int_as_float(__builtin_amdgcn_readlane(cx, i));
            const float sy = __int_as_float(__builtin_amdgcn_readlane(cy, i));
            const float sz = __int_as_float(__builtin_amdgcn_readlane(cz, i));
            const float sm = __int_as_float(__builtin_amdgcn_readlane(cm, i));

            const float dx = sx - xj;
            const float dy = sy - yj;
            const float dz = sz - zj;
            const float d2 = fmaf(dx, dx, fmaf(dy, dy, dz * dz)); // = (2d)^2
            // t = clip(d/0.5, 0, 200): coords pre-scaled by 2 -> t = sqrt(d2)
            const float tt = fminf(__builtin_amdgcn_sqrtf(d2), 200.0f);
            const unsigned lo   = (unsigned)tt;                   // trunc cvt
            const float    frac = __builtin_amdgcn_fractf(tt);
            float wp = sm * mjq;
            if (DIAG) wp = (c * 64 + i < t) ? wp : 0.0f;          // i<j on diagonal
            const unsigned q   = (unsigned)fmaf(wp, frac, 0.5f);  // -> bin lo+1
            const unsigned tot = (unsigned)(wp + 0.5f);
            const unsigned idx = (lo & 1u) * 201u + lo;
            const unsigned long long pack =
                ((unsigned long long)q << 32) | (unsigned long long)(tot - q);
            atomicAdd((unsigned long long*)&rep[idx], pack);      // ds_add_u64
        }
    }
}

__global__ __launch_bounds__(TILE) void saxs_hist_kernel(
    const float* __restrict__ posPred,
    const float* __restrict__ posTrue,
    const float* __restrict__ mask,
    unsigned long long* __restrict__ gh)
{
    const int t    = threadIdx.x;
    const int lane = t & 63;
    const int s    = blockIdx.y;               // 0 = pred, 1 = true
    const float* __restrict__ pos = s ? posTrue : posPred;
    unsigned long long* __restrict__ ghist = gh + s * HSTRIDE;

    // Decode triangular tile index -> (a, b), a <= b. Wave-uniform, once.
    int p = blockIdx.x;
    int a = 0;
    while (p >= NTILES - a) { p -= NTILES - a; ++a; }
    const int b = a + p;

    __shared__ unsigned long long sHist64[NREP * RSTRIDE / 2];   // 51456 B
    unsigned int* sHist = (unsigned int*)sHist64;
    for (int k = t; k < NREP * RSTRIDE; k += TILE) sHist[k] = 0u;

    // j-atom (one per thread) from tile b; coords pre-scaled by 2.
    const int jg = b * TILE + t;
    const float xj = 2.0f * pos[3 * jg];
    const float yj = 2.0f * pos[3 * jg + 1];
    const float zj = 2.0f * pos[3 * jg + 2];
    const float mjq = mask[jg] * QSCALE;

    __syncthreads();

    // lanes L and L+32 share a replica: atoms 32 apart (different residues,
    // weakly correlated distances) -> low same-address collision rate.
    unsigned int* __restrict__ rep = sHist + (t & (NREP - 1)) * RSTRIDE;

    if (a != b) accum_tile<false>(pos, mask, a * TILE, t, lane, xj, yj, zj, mjq, rep);
    else        accum_tile<true >(pos, mask, a * TILE, t, lane, xj, yj, zj, mjq, rep);

    __syncthreads();

    // Reduce replicas; per block per bin fits u32 (<= 65536 * 2^15 = 2^31).
    for (int k = t; k < NBINS; k += TILE) {
        unsigned int acc = 0;
        #pragma unroll
        for (int r = 0; r < NREP; ++r) {
            acc += sHist[r * RSTRIDE + k];                       // E[k]
            if (k > 0) acc += sHist[r * RSTRIDE + 202 + k - 1];  // O[k-1]
        }
        atomicAdd(&ghist[k], (unsigned long long)acc);           // global u64 add
    }
}

__global__ void saxs_loss_kernel(const unsigned long long* __restrict__ gh,
                                 float* __restrict__ out)
{
    const int lane = threadIdx.x;              // single wave of 64
    float hp[4], ht[4];
    float sp = 0.0f, st = 0.0f;
    #pragma unroll
    for (int r = 0; r < 4; ++r) {
        const int k = lane + 64 * r;
        float a = 0.0f, c = 0.0f;
        if (k < NBINS) {
            a = (float)gh[k];
            c = (float)gh[HSTRIDE + k];
        }
        hp[r] = a; ht[r] = c;
        sp += a; st += c;
    }
    #pragma unroll
    for (int off = 32; off > 0; off >>= 1) {
        sp += __shfl_xor(sp, off);
        st += __shfl_xor(st, off);
    }
    sp += 1e-12f;
    st += 1e-12f;
    float l = 0.0f;
    #pragma unroll
    for (int r = 0; r < 4; ++r) l += fabsf(hp[r] / sp - ht[r] / st);
    #pragma unroll
    for (int off = 32; off > 0; off >>= 1) l += __shfl_xor(l, off);
    if (lane == 0) out[0] = l;
}

extern "C" void kernel_launch(void* const* d_in, const int* in_sizes, int n_in,
                              void* d_out, int out_size, void* d_ws, size_t ws_size,
                              hipStream_t stream)
{
    const float* pred = (const float*)d_in[0];  // final_atom_positions [256,37,3]
    const float* tru  = (const float*)d_in[1];  // all_atom_positions   [256,37,3]
    const float* msk  = (const float*)d_in[2];  // all_atom_mask        [256,37]
    float* out = (float*)d_out;
    unsigned long long* ws = (unsigned long long*)d_ws;

    // ws is poisoned 0xAA before every timed launch — zero the histograms.
    hipMemsetAsync(d_ws, 0, 2 * HSTRIDE * sizeof(unsigned long long), stream);

    dim3 grid(TPAIRS, 2);
    saxs_hist_kernel<<<grid, dim3(TILE), 0, stream>>>(pred, tru, msk, ws);
    saxs_loss_kernel<<<dim3(1), dim3(64), 0, stream>>>(ws, out);
}

// Round 6
// 145.748 us; speedup vs baseline: 7.2772x; 1.0144x over previous
//
#include <hip/hip_runtime.h>

// SAXS loss: soft-binned pair-distance histograms for pred & true structures,
// normalized, then L1-summed. N = 256*37 = 9472 atoms = 37 tiles of 256 exactly.
// Symmetry: count i<j only (doubling cancels in normalization).
//
// R5 -> R6: R5 was latency-bound at ~3 blocks/CU (51.7 KB LDS), with real
// VALU ~37% and DS ~30% (VALUBusy derived counter is ~2x inflated on gfx950:
// gfx94x SIMD-16 formula). NREP 32->16 (25.7 KB -> ~6 blocks/CU) restores
// overlap; conflicts were shown NREP-insensitive (structural). Mask handling
// goes integer (tot = smi & vj). Loss computation fused via last-block-done
// counter -> single kernel + one memset. Accumulation stays all-integer:
// one native ds_add_u64 per pair packs the two adjacent-bin q15 weights.

#define TILE    256
#define NTILES  37                            // 9472 / 256, exact
#define TPAIRS  (NTILES * (NTILES + 1) / 2)   // 703 triangular tile pairs
#define NBINS   201
#define NREP    16                            // LDS histogram replicas
#define RSTRIDE 402                           // u32 words/replica: E=202, O=200
#define HSTRIDE 256                           // per-structure u64 hist stride in ws
#define QSCALE  32768.0f                      // q15

// Per-replica u32 layout at base r*RSTRIDE:
//   E[i] = base + i        (i 0..201): contributes to bin i   (E[201] dummy)
//   O[j] = base + 202 + j  (j 0..199): contributes to bin j+1
// u64 slot for (lo, lo+1): word idx = lo + 201*(lo&1) — always even (aligned).
// Reduce: bin k = E[k] + (k>0 ? O[k-1] : 0).

template<bool DIAG>
__device__ __forceinline__ void accum_tile(
    const float* __restrict__ pos, const float* __restrict__ mask,
    int aBase, int t, int lane,
    float xj, float yj, float zj, unsigned vj,
    unsigned int* __restrict__ rep)
{
    #pragma unroll
    for (int c = 0; c < 4; ++c) {
        const int ia = aBase + c * 64 + lane;
        const int cx = __float_as_int(2.0f * pos[3 * ia]);
        const int cy = __float_as_int(2.0f * pos[3 * ia + 1]);
        const int cz = __float_as_int(2.0f * pos[3 * ia + 2]);
        const int cmi = (int)(mask[ia] * QSCALE);   // integer q15 mask weight

        #pragma unroll 4
        for (int i = 0; i < 64; ++i) {              // dynamic-lane readlane
            const float sx = __int_as_float(__builtin_amdgcn_readlane(cx, i));
            const float sy = __int_as_float(__builtin_amdgcn_readlane(cy, i));
            const float sz = __int_as_float(__builtin_amdgcn_readlane(cz, i));
            const unsigned smi = (unsigned)__builtin_amdgcn_readlane(cmi, i);

            const float dx = sx - xj;
            const float dy = sy - yj;
            const float dz = sz - zj;
            const float d2 = fmaf(dx, dx, fmaf(dy, dy, dz * dz)); // = (2d)^2
            // t = clip(d/0.5, 0, 200): coords pre-scaled by 2 -> t = sqrt(d2)
            const float tt = fminf(__builtin_amdgcn_sqrtf(d2), 200.0f);
            const unsigned lo   = (unsigned)tt;                   // trunc cvt
            const float    frac = __builtin_amdgcn_fractf(tt);
            // masks are 0/1 floats -> pair weight in q15 via bitwise select
            unsigned tot = smi & vj;
            if (DIAG) tot = (c * 64 + i < t) ? tot : 0u;          // i<j on diag
            const float    wpf = (float)tot;
            const unsigned q   = (unsigned)fmaf(wpf, frac, 0.5f); // -> bin lo+1
            const unsigned idx = (lo & 1u) * 201u + lo;
            const unsigned long long pack =
                ((unsigned long long)q << 32) | (unsigned long long)(tot - q);
            atomicAdd((unsigned long long*)&rep[idx], pack);      // ds_add_u64
        }
    }
}

__global__ __launch_bounds__(TILE) void saxs_hist_kernel(
    const float* __restrict__ posPred,
    const float* __restrict__ posTrue,
    const float* __restrict__ mask,
    unsigned long long* __restrict__ gh,
    unsigned int* __restrict__ counter,
    float* __restrict__ out)
{
    const int t    = threadIdx.x;
    const int lane = t & 63;
    const int s    = blockIdx.y;               // 0 = pred, 1 = true
    const float* __restrict__ pos = s ? posTrue : posPred;
    unsigned long long* __restrict__ ghist = gh + s * HSTRIDE;

    // Decode triangular tile index -> (a, b), a <= b. Wave-uniform, once.
    int p = blockIdx.x;
    int a = 0;
    while (p >= NTILES - a) { p -= NTILES - a; ++a; }
    const int b = a + p;

    __shared__ unsigned long long sHist64[NREP * RSTRIDE / 2];   // 25728 B
    unsigned int* sHist = (unsigned int*)sHist64;
    for (int k = t; k < NREP * RSTRIDE; k += TILE) sHist[k] = 0u;

    // j-atom (one per thread) from tile b; coords pre-scaled by 2.
    const int jg = b * TILE + t;
    const float xj = 2.0f * pos[3 * jg];
    const float yj = 2.0f * pos[3 * jg + 1];
    const float zj = 2.0f * pos[3 * jg + 2];
    const unsigned vj = (mask[jg] != 0.0f) ? 0xFFFFFFFFu : 0u;

    __syncthreads();

    unsigned int* __restrict__ rep = sHist + (t & (NREP - 1)) * RSTRIDE;

    if (a != b) accum_tile<false>(pos, mask, a * TILE, t, lane, xj, yj, zj, vj, rep);
    else        accum_tile<true >(pos, mask, a * TILE, t, lane, xj, yj, zj, vj, rep);

    __syncthreads();

    // Reduce replicas; per block per bin fits u32 (<= 65536 * 2^15 = 2^31).
    for (int k = t; k < NBINS; k += TILE) {
        unsigned int acc = 0;
        #pragma unroll
        for (int r = 0; r < NREP; ++r) {
            acc += sHist[r * RSTRIDE + k];                       // E[k]
            if (k > 0) acc += sHist[r * RSTRIDE + 202 + k - 1];  // O[k-1]
        }
        atomicAdd(&ghist[k], (unsigned long long)acc);           // global u64 add
    }

    // ---- fused loss: last block to finish computes the L1 of normalized hists
    __syncthreads();                       // drains vmcnt for all waves (barrier)
    __shared__ int sLast;
    if (t == 0) {
        __threadfence();                   // publish our adds (device scope)
        const unsigned prev = __hip_atomic_fetch_add(
            counter, 1u, __ATOMIC_ACQ_REL, __HIP_MEMORY_SCOPE_AGENT);
        sLast = (prev == 2u * TPAIRS - 1u);
    }
    __syncthreads();
    if (sLast && t < 64) {
        const int ln = t;                  // single wave of 64
        float hp[4], ht[4];
        float sp = 0.0f, st = 0.0f;
        #pragma unroll
        for (int r = 0; r < 4; ++r) {
            const int k = ln + 64 * r;
            float av = 0.0f, cv = 0.0f;
            if (k < NBINS) {
                av = (float)__hip_atomic_load(&gh[k],           __ATOMIC_RELAXED,
                                              __HIP_MEMORY_SCOPE_AGENT);
                cv = (float)__hip_atomic_load(&gh[HSTRIDE + k], __ATOMIC_RELAXED,
                                              __HIP_MEMORY_SCOPE_AGENT);
            }
            hp[r] = av; ht[r] = cv;
            sp += av; st += cv;
        }
        #pragma unroll
        for (int off = 32; off > 0; off >>= 1) {
            sp += __shfl_xor(sp, off);
            st += __shfl_xor(st, off);
        }
        sp += 1e-12f;
        st += 1e-12f;
        float l = 0.0f;
        #pragma unroll
        for (int r = 0; r < 4; ++r) l += fabsf(hp[r] / sp - ht[r] / st);
        #pragma unroll
        for (int off = 32; off > 0; off >>= 1) l += __shfl_xor(l, off);
        if (ln == 0) out[0] = l;
    }
}

extern "C" void kernel_launch(void* const* d_in, const int* in_sizes, int n_in,
                              void* d_out, int out_size, void* d_ws, size_t ws_size,
                              hipStream_t stream)
{
    const float* pred = (const float*)d_in[0];  // final_atom_positions [256,37,3]
    const float* tru  = (const float*)d_in[1];  // all_atom_positions   [256,37,3]
    const float* msk  = (const float*)d_in[2];  // all_atom_mask        [256,37]
    float* out = (float*)d_out;
    unsigned long long* ws = (unsigned long long*)d_ws;
    unsigned int* counter = (unsigned int*)(ws + 2 * HSTRIDE);

    // ws is poisoned 0xAA before every timed launch — zero hists + counter.
    hipMemsetAsync(d_ws, 0, (2 * HSTRIDE + 1) * sizeof(unsigned long long), stream);

    dim3 grid(TPAIRS, 2);
    saxs_hist_kernel<<<grid, dim3(TILE), 0, stream>>>(pred, tru, msk, ws, counter, out);
}

// Round 7
// 140.041 us; speedup vs baseline: 7.5738x; 1.0408x over previous
//
#include <hip/hip_runtime.h>

// SAXS loss: soft-binned pair-distance histograms for pred & true structures,
// normalized, then L1-summed. N = 256*37 = 9472 atoms = 37 tiles of 256 exactly.
// Symmetry: count i<j only (doubling cancels in normalization).
//
// R6 -> R7: ds_add_u64 touched a bank-PAIR per lane (64 lanes over 16 bank
// pairs -> ~8+ bank-cycles/instr; SQ_LDS_BANK_CONFLICT invariant at 11.96M
// across NREP 16/32 = structural). Switch to ONE ds_add_u32 per pair: both
// adjacent-bin weights packed as two q8 16-bit fields (low16 -> bin lo,
// high16 -> bin lo+1). Replica stride 201 with NREP=32 makes lane L's base
// bank 9*(L&31) mod 32 — a full-bank permutation -> near-uniform traffic.
// Reduce unpacks: bin k = sum_r low(W[r][k]) + high(W[r][k-1]).

#define TILE    256
#define NTILES  37                            // 9472 / 256, exact
#define TPAIRS  (NTILES * (NTILES + 1) / 2)   // 703 triangular tile pairs
#define NBINS   201
#define NREP    32                            // LDS histogram replicas
#define RSTRIDE 201                           // u32 words per replica
#define HSTRIDE 256                           // per-structure u64 hist stride in ws
#define QSCALE  256.0f                        // q8 fixed point

template<bool DIAG>
__device__ __forceinline__ void accum_tile(
    const float* __restrict__ pos, const float* __restrict__ mask,
    int aBase, int t, int lane,
    float xj, float yj, float zj, unsigned vj,
    unsigned int* __restrict__ rep)
{
    #pragma unroll
    for (int c = 0; c < 4; ++c) {
        const int ia = aBase + c * 64 + lane;
        const int cx = __float_as_int(2.0f * pos[3 * ia]);
        const int cy = __float_as_int(2.0f * pos[3 * ia + 1]);
        const int cz = __float_as_int(2.0f * pos[3 * ia + 2]);
        const int cmi = (int)(mask[ia] * QSCALE);   // integer q8 mask weight

        #pragma unroll 4
        for (int i = 0; i < 64; ++i) {              // dynamic-lane readlane
            const float sx = __int_as_float(__builtin_amdgcn_readlane(cx, i));
            const float sy = __int_as_float(__builtin_amdgcn_readlane(cy, i));
            const float sz = __int_as_float(__builtin_amdgcn_readlane(cz, i));
            const unsigned smi = (unsigned)__builtin_amdgcn_readlane(cmi, i);

            const float dx = sx - xj;
            const float dy = sy - yj;
            const float dz = sz - zj;
            const float d2 = fmaf(dx, dx, fmaf(dy, dy, dz * dz)); // = (2d)^2
            // t = clip(d/0.5, 0, 200): coords pre-scaled by 2 -> t = sqrt(d2)
            const float tt = fminf(__builtin_amdgcn_sqrtf(d2), 200.0f);
            const unsigned lo   = (unsigned)tt;                   // trunc cvt
            const float    frac = __builtin_amdgcn_fractf(tt);
            // masks are 0/1 floats -> q8 pair weight via bitwise select
            unsigned tot = smi & vj;
            if (DIAG) tot = (c * 64 + i < t) ? tot : 0u;          // i<j on diag
            const float    wpf = (float)tot;
            const unsigned q   = (unsigned)fmaf(wpf, frac, 0.5f); // -> bin lo+1
            const unsigned pack = (q << 16) + (tot - q);          // [hi|lo] fields
            atomicAdd(&rep[lo], pack);                            // ds_add_u32
        }
    }
}

__global__ __launch_bounds__(TILE) void saxs_hist_kernel(
    const float* __restrict__ posPred,
    const float* __restrict__ posTrue,
    const float* __restrict__ mask,
    unsigned long long* __restrict__ gh,
    unsigned int* __restrict__ counter,
    float* __restrict__ out)
{
    const int t    = threadIdx.x;
    const int lane = t & 63;
    const int s    = blockIdx.y;               // 0 = pred, 1 = true
    const float* __restrict__ pos = s ? posTrue : posPred;
    unsigned long long* __restrict__ ghist = gh + s * HSTRIDE;

    // Decode triangular tile index -> (a, b), a <= b. Wave-uniform, once.
    int p = blockIdx.x;
    int a = 0;
    while (p >= NTILES - a) { p -= NTILES - a; ++a; }
    const int b = a + p;

    __shared__ unsigned int sHist[NREP * RSTRIDE];   // 25728 B -> 6 blocks/CU
    for (int k = t; k < NREP * RSTRIDE; k += TILE) sHist[k] = 0u;

    // j-atom (one per thread) from tile b; coords pre-scaled by 2.
    const int jg = b * TILE + t;
    const float xj = 2.0f * pos[3 * jg];
    const float yj = 2.0f * pos[3 * jg + 1];
    const float zj = 2.0f * pos[3 * jg + 2];
    const unsigned vj = (mask[jg] != 0.0f) ? 0xFFFFFFFFu : 0u;

    __syncthreads();

    unsigned int* __restrict__ rep = sHist + (t & (NREP - 1)) * RSTRIDE;

    if (a != b) accum_tile<false>(pos, mask, a * TILE, t, lane, xj, yj, zj, vj, rep);
    else        accum_tile<true >(pos, mask, a * TILE, t, lane, xj, yj, zj, vj, rep);

    __syncthreads();

    // Reduce replicas: bin k = sum_r low16(W[r][k]) + high16(W[r][k-1]).
    // Per block per bin <= 65536 pairs * 256 = 2^24 -> fits u32 easily.
    for (int k = t; k < NBINS; k += TILE) {
        unsigned int acc = 0;
        #pragma unroll
        for (int r = 0; r < NREP; ++r) {
            acc += sHist[r * RSTRIDE + k] & 0xFFFFu;
            if (k > 0) acc += sHist[r * RSTRIDE + k - 1] >> 16;
        }
        atomicAdd(&ghist[k], (unsigned long long)acc);   // global u64 add
    }

    // ---- fused loss: last block to finish computes the L1 of normalized hists
    __syncthreads();
    __shared__ int sLast;
    if (t == 0) {
        __threadfence();                   // publish our adds (device scope)
        const unsigned prev = __hip_atomic_fetch_add(
            counter, 1u, __ATOMIC_ACQ_REL, __HIP_MEMORY_SCOPE_AGENT);
        sLast = (prev == 2u * TPAIRS - 1u);
    }
    __syncthreads();
    if (sLast && t < 64) {
        const int ln = t;                  // single wave of 64
        float hp[4], ht[4];
        float sp = 0.0f, st = 0.0f;
        #pragma unroll
        for (int r = 0; r < 4; ++r) {
            const int k = ln + 64 * r;
            float av = 0.0f, cv = 0.0f;
            if (k < NBINS) {
                av = (float)__hip_atomic_load(&gh[k],           __ATOMIC_RELAXED,
                                              __HIP_MEMORY_SCOPE_AGENT);
                cv = (float)__hip_atomic_load(&gh[HSTRIDE + k], __ATOMIC_RELAXED,
                                              __HIP_MEMORY_SCOPE_AGENT);
            }
            hp[r] = av; ht[r] = cv;
            sp += av; st += cv;
        }
        #pragma unroll
        for (int off = 32; off > 0; off >>= 1) {
            sp += __shfl_xor(sp, off);
            st += __shfl_xor(st, off);
        }
        sp += 1e-12f;
        st += 1e-12f;
        float l = 0.0f;
        #pragma unroll
        for (int r = 0; r < 4; ++r) l += fabsf(hp[r] / sp - ht[r] / st);
        #pragma unroll
        for (int off = 32; off > 0; off >>= 1) l += __shfl_xor(l, off);
        if (ln == 0) out[0] = l;
    }
}

extern "C" void kernel_launch(void* const* d_in, const int* in_sizes, int n_in,
                              void* d_out, int out_size, void* d_ws, size_t ws_size,
                              hipStream_t stream)
{
    const float* pred = (const float*)d_in[0];  // final_atom_positions [256,37,3]
    const float* tru  = (const float*)d_in[1];  // all_atom_positions   [256,37,3]
    const float* msk  = (const float*)d_in[2];  // all_atom_mask        [256,37]
    float* out = (float*)d_out;
    unsigned long long* ws = (unsigned long long*)d_ws;
    unsigned int* counter = (unsigned int*)(ws + 2 * HSTRIDE);

    // ws is poisoned 0xAA before every timed launch — zero hists + counter.
    hipMemsetAsync(d_ws, 0, (2 * HSTRIDE + 1) * sizeof(unsigned long long), stream);

    dim3 grid(TPAIRS, 2);
    saxs_hist_kernel<<<grid, dim3(TILE), 0, stream>>>(pred, tru, msk, ws, counter, out);
}

// Round 8
// 135.426 us; speedup vs baseline: 7.8319x; 1.0341x over previous
//
#include <hip/hip_runtime.h>

// SAXS loss: soft-binned pair-distance histograms for pred & true structures,
// normalized, then L1-summed. N = 256*37 = 9472 atoms = 37 tiles of 256 exactly.
// Symmetry: count i<j only (doubling cancels in normalization).
//
// R7 -> R8: fuse BOTH structures into one pass. Per inner iteration a lane
// handles the same (i,j) atom pair for pred AND true: mask work (tot, wpf,
// diag cndmask) is shared (masks identical across structures), readlanes
// 8 -> 7 per two pairs, loop/branch overhead per unit work halves, and the
// two independent sqrt->bin chains double ILP. Grid 1406 -> 703 blocks.
// Accumulation: q8 weights packed in u16 fields, one ds_add_u32 per
// structure-pair; 16 LDS replicas per structure (25.7 KB total).

#define TILE    256
#define NTILES  37                            // 9472 / 256, exact
#define TPAIRS  (NTILES * (NTILES + 1) / 2)   // 703 triangular tile pairs
#define NBINS   201
#define NREP    16                            // LDS replicas per structure
#define RSTRIDE 201                           // u32 words per replica
#define SOFF    (NREP * RSTRIDE)              // LDS offset of true-structure hists
#define HSTRIDE 256                           // per-structure u64 hist stride in ws
#define QSCALE  256.0f                        // q8 fixed point

template<bool DIAG>
__device__ __forceinline__ void accum_tile(
    const float* __restrict__ posP, const float* __restrict__ posT,
    const float* __restrict__ mask,
    int aBase, int t, int lane,
    float xjp, float yjp, float zjp,
    float xjt, float yjt, float zjt, unsigned vj,
    unsigned int* __restrict__ repP, unsigned int* __restrict__ repT)
{
    #pragma unroll
    for (int c = 0; c < 4; ++c) {
        const int ia = aBase + c * 64 + lane;
        const int cxp = __float_as_int(2.0f * posP[3 * ia]);
        const int cyp = __float_as_int(2.0f * posP[3 * ia + 1]);
        const int czp = __float_as_int(2.0f * posP[3 * ia + 2]);
        const int cxt = __float_as_int(2.0f * posT[3 * ia]);
        const int cyt = __float_as_int(2.0f * posT[3 * ia + 1]);
        const int czt = __float_as_int(2.0f * posT[3 * ia + 2]);
        const int cmi = (int)(mask[ia] * QSCALE);   // integer q8 mask weight

        #pragma unroll 4
        for (int i = 0; i < 64; ++i) {              // dynamic-lane readlane
            const float sxp = __int_as_float(__builtin_amdgcn_readlane(cxp, i));
            const float syp = __int_as_float(__builtin_amdgcn_readlane(cyp, i));
            const float szp = __int_as_float(__builtin_amdgcn_readlane(czp, i));
            const float sxt = __int_as_float(__builtin_amdgcn_readlane(cxt, i));
            const float syt = __int_as_float(__builtin_amdgcn_readlane(cyt, i));
            const float szt = __int_as_float(__builtin_amdgcn_readlane(czt, i));
            const unsigned smi = (unsigned)__builtin_amdgcn_readlane(cmi, i);

            // shared mask work (masks identical for pred/true)
            unsigned tot = smi & vj;                 // 0 or 256 (q8)
            if (DIAG) tot = (c * 64 + i < t) ? tot : 0u;   // i<j on diag
            const float wpf = (float)tot;

            // pred chain
            const float dxp = sxp - xjp;
            const float dyp = syp - yjp;
            const float dzp = szp - zjp;
            const float d2p = fmaf(dxp, dxp, fmaf(dyp, dyp, dzp * dzp));
            const float ttp = fminf(__builtin_amdgcn_sqrtf(d2p), 200.0f);
            const unsigned lop = (unsigned)ttp;
            const float    frp = __builtin_amdgcn_fractf(ttp);
            const unsigned qp  = (unsigned)fmaf(wpf, frp, 0.5f);
            atomicAdd(&repP[lop], (qp << 16) + (tot - qp));      // ds_add_u32

            // true chain (independent -> ILP)
            const float dxt = sxt - xjt;
            const float dyt = syt - yjt;
            const float dzt = szt - zjt;
            const float d2t = fmaf(dxt, dxt, fmaf(dyt, dyt, dzt * dzt));
            const float ttt = fminf(__builtin_amdgcn_sqrtf(d2t), 200.0f);
            const unsigned lot = (unsigned)ttt;
            const float    frt = __builtin_amdgcn_fractf(ttt);
            const unsigned qt  = (unsigned)fmaf(wpf, frt, 0.5f);
            atomicAdd(&repT[lot], (qt << 16) + (tot - qt));      // ds_add_u32
        }
    }
}

__global__ __launch_bounds__(TILE) void saxs_hist_kernel(
    const float* __restrict__ posPred,
    const float* __restrict__ posTrue,
    const float* __restrict__ mask,
    unsigned long long* __restrict__ gh,
    unsigned int* __restrict__ counter,
    float* __restrict__ out)
{
    const int t    = threadIdx.x;
    const int lane = t & 63;

    // Decode triangular tile index -> (a, b), a <= b. Wave-uniform, once.
    int p = blockIdx.x;
    int a = 0;
    while (p >= NTILES - a) { p -= NTILES - a; ++a; }
    const int b = a + p;

    __shared__ unsigned int sHist[2 * NREP * RSTRIDE];   // 25728 B -> 6 blocks/CU
    for (int k = t; k < 2 * NREP * RSTRIDE; k += TILE) sHist[k] = 0u;

    // j-atom (one per thread) from tile b, both structures; coords pre-scaled x2.
    const int jg = b * TILE + t;
    const float xjp = 2.0f * posPred[3 * jg];
    const float yjp = 2.0f * posPred[3 * jg + 1];
    const float zjp = 2.0f * posPred[3 * jg + 2];
    const float xjt = 2.0f * posTrue[3 * jg];
    const float yjt = 2.0f * posTrue[3 * jg + 1];
    const float zjt = 2.0f * posTrue[3 * jg + 2];
    const unsigned vj = (mask[jg] != 0.0f) ? 0xFFFFFFFFu : 0u;

    __syncthreads();

    unsigned int* __restrict__ repP = sHist + (t & (NREP - 1)) * RSTRIDE;
    unsigned int* __restrict__ repT = repP + SOFF;

    if (a != b) accum_tile<false>(posPred, posTrue, mask, a * TILE, t, lane,
                                  xjp, yjp, zjp, xjt, yjt, zjt, vj, repP, repT);
    else        accum_tile<true >(posPred, posTrue, mask, a * TILE, t, lane,
                                  xjp, yjp, zjp, xjt, yjt, zjt, vj, repP, repT);

    __syncthreads();

    // Reduce replicas: bin k = sum_r low16(W[r][k]) + high16(W[r][k-1]);
    // both structures (402 bins total), one global u64 add per bin per block.
    for (int k = t; k < 2 * NBINS; k += TILE) {
        const int s  = (k < NBINS) ? 0 : 1;
        const int kk = k - s * NBINS;
        const unsigned int* h = sHist + s * SOFF;
        unsigned int acc = 0;
        #pragma unroll
        for (int r = 0; r < NREP; ++r) {
            acc += h[r * RSTRIDE + kk] & 0xFFFFu;
            if (kk > 0) acc += h[r * RSTRIDE + kk - 1] >> 16;
        }
        atomicAdd(&gh[s * HSTRIDE + kk], (unsigned long long)acc);
    }

    // ---- fused loss: last block to finish computes the L1 of normalized hists
    __syncthreads();
    __shared__ int sLast;
    if (t == 0) {
        __threadfence();                   // publish our adds (device scope)
        const unsigned prev = __hip_atomic_fetch_add(
            counter, 1u, __ATOMIC_ACQ_REL, __HIP_MEMORY_SCOPE_AGENT);
        sLast = (prev == TPAIRS - 1u);
    }
    __syncthreads();
    if (sLast && t < 64) {
        const int ln = t;                  // single wave of 64
        float hp[4], ht[4];
        float sp = 0.0f, st = 0.0f;
        #pragma unroll
        for (int r = 0; r < 4; ++r) {
            const int k = ln + 64 * r;
            float av = 0.0f, cv = 0.0f;
            if (k < NBINS) {
                av = (float)__hip_atomic_load(&gh[k],           __ATOMIC_RELAXED,
                                              __HIP_MEMORY_SCOPE_AGENT);
                cv = (float)__hip_atomic_load(&gh[HSTRIDE + k], __ATOMIC_RELAXED,
                                              __HIP_MEMORY_SCOPE_AGENT);
            }
            hp[r] = av; ht[r] = cv;
            sp += av; st += cv;
        }
        #pragma unroll
        for (int off = 32; off > 0; off >>= 1) {
            sp += __shfl_xor(sp, off);
            st += __shfl_xor(st, off);
        }
        sp += 1e-12f;
        st += 1e-12f;
        float l = 0.0f;
        #pragma unroll
        for (int r = 0; r < 4; ++r) l += fabsf(hp[r] / sp - ht[r] / st);
        #pragma unroll
        for (int off = 32; off > 0; off >>= 1) l += __shfl_xor(l, off);
        if (ln == 0) out[0] = l;
    }
}

extern "C" void kernel_launch(void* const* d_in, const int* in_sizes, int n_in,
                              void* d_out, int out_size, void* d_ws, size_t ws_size,
                              hipStream_t stream)
{
    const float* pred = (const float*)d_in[0];  // final_atom_positions [256,37,3]
    const float* tru  = (const float*)d_in[1];  // all_atom_positions   [256,37,3]
    const float* msk  = (const float*)d_in[2];  // all_atom_mask        [256,37]
    float* out = (float*)d_out;
    unsigned long long* ws = (unsigned long long*)d_ws;
    unsigned int* counter = (unsigned int*)(ws + 2 * HSTRIDE);

    // ws is poisoned 0xAA before every timed launch — zero hists + counter.
    hipMemsetAsync(d_ws, 0, (2 * HSTRIDE + 1) * sizeof(unsigned long long), stream);

    saxs_hist_kernel<<<dim3(TPAIRS), dim3(TILE), 0, stream>>>(
        pred, tru, msk, ws, counter, out);
}

// Round 9
// 131.969 us; speedup vs baseline: 8.0370x; 1.0262x over previous
//
#include <hip/hip_runtime.h>

// SAXS loss: soft-binned pair-distance histograms for pred & true structures,
// normalized, then L1-summed. N = 256*37 = 9472 atoms = 37 tiles of 256 exactly.
// Symmetry: count i<j only (doubling cancels in normalization).
//
// R8 -> R9: R8's structure fusion halved the grid to 703 blocks -> 2.75
// blocks/CU (21.8% occupancy) and the kernel went latency-bound (VALU issue
// only ~26% of cycles by static count). Split each tile-pair's i-loop across
// 2 blocks (grid 703x2, 128 i-atoms each): per-pair efficiency of R8 with
// R7's 5.5 blocks/CU of latency-hiding TLP. LDS footprint unchanged
// (25.7 KB, cap 6 blocks/CU). Accumulation: q8 weights in u16 fields, one
// ds_add_u32 per structure-pair, 16 replicas/structure.

#define TILE    256
#define NTILES  37                            // 9472 / 256, exact
#define TPAIRS  (NTILES * (NTILES + 1) / 2)   // 703 triangular tile pairs
#define NBINS   201
#define NREP    16                            // LDS replicas per structure
#define RSTRIDE 201                           // u32 words per replica
#define SOFF    (NREP * RSTRIDE)              // LDS offset of true-structure hists
#define HSTRIDE 256                           // per-structure u64 hist stride in ws
#define QSCALE  256.0f                        // q8 fixed point

template<bool DIAG>
__device__ __forceinline__ void accum_tile(
    const float* __restrict__ posP, const float* __restrict__ posT,
    const float* __restrict__ mask,
    int aBase, int c0, int t, int lane,
    float xjp, float yjp, float zjp,
    float xjt, float yjt, float zjt, unsigned vj,
    unsigned int* __restrict__ repP, unsigned int* __restrict__ repT)
{
    #pragma unroll
    for (int c = c0; c < c0 + 2; ++c) {
        const int ia = aBase + c * 64 + lane;
        const int cxp = __float_as_int(2.0f * posP[3 * ia]);
        const int cyp = __float_as_int(2.0f * posP[3 * ia + 1]);
        const int czp = __float_as_int(2.0f * posP[3 * ia + 2]);
        const int cxt = __float_as_int(2.0f * posT[3 * ia]);
        const int cyt = __float_as_int(2.0f * posT[3 * ia + 1]);
        const int czt = __float_as_int(2.0f * posT[3 * ia + 2]);
        const int cmi = (int)(mask[ia] * QSCALE);   // integer q8 mask weight

        #pragma unroll 4
        for (int i = 0; i < 64; ++i) {              // dynamic-lane readlane
            const float sxp = __int_as_float(__builtin_amdgcn_readlane(cxp, i));
            const float syp = __int_as_float(__builtin_amdgcn_readlane(cyp, i));
            const float szp = __int_as_float(__builtin_amdgcn_readlane(czp, i));
            const float sxt = __int_as_float(__builtin_amdgcn_readlane(cxt, i));
            const float syt = __int_as_float(__builtin_amdgcn_readlane(cyt, i));
            const float szt = __int_as_float(__builtin_amdgcn_readlane(czt, i));
            const unsigned smi = (unsigned)__builtin_amdgcn_readlane(cmi, i);

            // shared mask work (masks identical for pred/true)
            unsigned tot = smi & vj;                 // 0 or 256 (q8)
            if (DIAG) tot = (c * 64 + i < t) ? tot : 0u;   // i<j on diag
            const float wpf = (float)tot;

            // pred chain
            const float dxp = sxp - xjp;
            const float dyp = syp - yjp;
            const float dzp = szp - zjp;
            const float d2p = fmaf(dxp, dxp, fmaf(dyp, dyp, dzp * dzp));
            const float ttp = fminf(__builtin_amdgcn_sqrtf(d2p), 200.0f);
            const unsigned lop = (unsigned)ttp;
            const float    frp = __builtin_amdgcn_fractf(ttp);
            const unsigned qp  = (unsigned)fmaf(wpf, frp, 0.5f);
            atomicAdd(&repP[lop], (qp << 16) + (tot - qp));      // ds_add_u32

            // true chain (independent -> ILP)
            const float dxt = sxt - xjt;
            const float dyt = syt - yjt;
            const float dzt = szt - zjt;
            const float d2t = fmaf(dxt, dxt, fmaf(dyt, dyt, dzt * dzt));
            const float ttt = fminf(__builtin_amdgcn_sqrtf(d2t), 200.0f);
            const unsigned lot = (unsigned)ttt;
            const float    frt = __builtin_amdgcn_fractf(ttt);
            const unsigned qt  = (unsigned)fmaf(wpf, frt, 0.5f);
            atomicAdd(&repT[lot], (qt << 16) + (tot - qt));      // ds_add_u32
        }
    }
}

__global__ __launch_bounds__(TILE) void saxs_hist_kernel(
    const float* __restrict__ posPred,
    const float* __restrict__ posTrue,
    const float* __restrict__ mask,
    unsigned long long* __restrict__ gh,
    unsigned int* __restrict__ counter,
    float* __restrict__ out)
{
    const int t    = threadIdx.x;
    const int lane = t & 63;
    const int c0   = 2 * blockIdx.y;           // i-chunk half: {0,1} or {2,3}

    // Decode triangular tile index -> (a, b), a <= b. Wave-uniform, once.
    int p = blockIdx.x;
    int a = 0;
    while (p >= NTILES - a) { p -= NTILES - a; ++a; }
    const int b = a + p;

    __shared__ unsigned int sHist[2 * NREP * RSTRIDE];   // 25728 B -> 6 blocks/CU
    for (int k = t; k < 2 * NREP * RSTRIDE; k += TILE) sHist[k] = 0u;

    // j-atom (one per thread) from tile b, both structures; coords pre-scaled x2.
    const int jg = b * TILE + t;
    const float xjp = 2.0f * posPred[3 * jg];
    const float yjp = 2.0f * posPred[3 * jg + 1];
    const float zjp = 2.0f * posPred[3 * jg + 2];
    const float xjt = 2.0f * posTrue[3 * jg];
    const float yjt = 2.0f * posTrue[3 * jg + 1];
    const float zjt = 2.0f * posTrue[3 * jg + 2];
    const unsigned vj = (mask[jg] != 0.0f) ? 0xFFFFFFFFu : 0u;

    __syncthreads();

    unsigned int* __restrict__ repP = sHist + (t & (NREP - 1)) * RSTRIDE;
    unsigned int* __restrict__ repT = repP + SOFF;

    if (a != b) accum_tile<false>(posPred, posTrue, mask, a * TILE, c0, t, lane,
                                  xjp, yjp, zjp, xjt, yjt, zjt, vj, repP, repT);
    else        accum_tile<true >(posPred, posTrue, mask, a * TILE, c0, t, lane,
                                  xjp, yjp, zjp, xjt, yjt, zjt, vj, repP, repT);

    __syncthreads();

    // Reduce replicas: bin k = sum_r low16(W[r][k]) + high16(W[r][k-1]);
    // both structures (402 bins total), one global u64 add per bin per block.
    for (int k = t; k < 2 * NBINS; k += TILE) {
        const int s  = (k < NBINS) ? 0 : 1;
        const int kk = k - s * NBINS;
        const unsigned int* h = sHist + s * SOFF;
        unsigned int acc = 0;
        #pragma unroll
        for (int r = 0; r < NREP; ++r) {
            acc += h[r * RSTRIDE + kk] & 0xFFFFu;
            if (kk > 0) acc += h[r * RSTRIDE + kk - 1] >> 16;
        }
        atomicAdd(&gh[s * HSTRIDE + kk], (unsigned long long)acc);
    }

    // ---- fused loss: last block to finish computes the L1 of normalized hists
    __syncthreads();
    __shared__ int sLast;
    if (t == 0) {
        __threadfence();                   // publish our adds (device scope)
        const unsigned prev = __hip_atomic_fetch_add(
            counter, 1u, __ATOMIC_ACQ_REL, __HIP_MEMORY_SCOPE_AGENT);
        sLast = (prev == 2u * TPAIRS - 1u);
    }
    __syncthreads();
    if (sLast && t < 64) {
        const int ln = t;                  // single wave of 64
        float hp[4], ht[4];
        float sp = 0.0f, st = 0.0f;
        #pragma unroll
        for (int r = 0; r < 4; ++r) {
            const int k = ln + 64 * r;
            float av = 0.0f, cv = 0.0f;
            if (k < NBINS) {
                av = (float)__hip_atomic_load(&gh[k],           __ATOMIC_RELAXED,
                                              __HIP_MEMORY_SCOPE_AGENT);
                cv = (float)__hip_atomic_load(&gh[HSTRIDE + k], __ATOMIC_RELAXED,
                                              __HIP_MEMORY_SCOPE_AGENT);
            }
            hp[r] = av; ht[r] = cv;
            sp += av; st += cv;
        }
        #pragma unroll
        for (int off = 32; off > 0; off >>= 1) {
            sp += __shfl_xor(sp, off);
            st += __shfl_xor(st, off);
        }
        sp += 1e-12f;
        st += 1e-12f;
        float l = 0.0f;
        #pragma unroll
        for (int r = 0; r < 4; ++r) l += fabsf(hp[r] / sp - ht[r] / st);
        #pragma unroll
        for (int off = 32; off > 0; off >>= 1) l += __shfl_xor(l, off);
        if (ln == 0) out[0] = l;
    }
}

extern "C" void kernel_launch(void* const* d_in, const int* in_sizes, int n_in,
                              void* d_out, int out_size, void* d_ws, size_t ws_size,
                              hipStream_t stream)
{
    const float* pred = (const float*)d_in[0];  // final_atom_positions [256,37,3]
    const float* tru  = (const float*)d_in[1];  // all_atom_positions   [256,37,3]
    const float* msk  = (const float*)d_in[2];  // all_atom_mask        [256,37]
    float* out = (float*)d_out;
    unsigned long long* ws = (unsigned long long*)d_ws;
    unsigned int* counter = (unsigned int*)(ws + 2 * HSTRIDE);

    // ws is poisoned 0xAA before every timed launch — zero hists + counter.
    hipMemsetAsync(d_ws, 0, (2 * HSTRIDE + 1) * sizeof(unsigned long long), stream);

    saxs_hist_kernel<<<dim3(TPAIRS, 2), dim3(TILE), 0, stream>>>(
        pred, tru, msk, ws, counter, out);
}

// Round 10
// 127.815 us; speedup vs baseline: 8.2982x; 1.0325x over previous
//
#include <hip/hip_runtime.h>

// SAXS loss: soft-binned pair-distance histograms for pred & true structures,
// normalized, then L1-summed. N = 256*37 = 9472 atoms = 37 tiles of 256 exactly.
// Symmetry: count i<j only (doubling cancels in normalization).
//
// R9 -> R10: VALUBusy ~70% was the only near-saturated pipe; occupancy fix
// (R9) proved latency wasn't the issue. Cut VALU issue: (1) i-atom data is
// wave-uniform -> SMEM s_load into SGPRs (readfirstlane-forced base) instead
// of 7 v_readlanes + hazards; (2) pred/true chains packed as float2 ->
// v_pk_{sub,fma,mul}_f32 halves the sub/fma ops; x4 distance scale folded
// into one pk_mul (replaces 6 scalar pre-scales); (3) mask test on SALU.
// Accumulation unchanged: q8 weights in u16 fields, one ds_add_u32 per
// structure-pair, 16 LDS replicas/structure, grid (703,2), 128 i per block.

#define TILE    256
#define NTILES  37                            // 9472 / 256, exact
#define TPAIRS  (NTILES * (NTILES + 1) / 2)   // 703 triangular tile pairs
#define NBINS   201
#define NREP    16                            // LDS replicas per structure
#define RSTRIDE 201                           // u32 words per replica
#define SOFF    (NREP * RSTRIDE)              // LDS offset of true-structure hists
#define HSTRIDE 256                           // per-structure u64 hist stride in ws

typedef float v2f __attribute__((ext_vector_type(2)));

template<bool DIAG>
__device__ __forceinline__ void accum_tile(
    const float* __restrict__ posP, const float* __restrict__ posT,
    const float* __restrict__ mask,
    int i0,                                    // uniform global first i-atom
    int iLoc0,                                 // tile-local first i (DIAG test)
    int t,
    v2f xj, v2f yj, v2f zj, unsigned vj,
    unsigned int* __restrict__ repP, unsigned int* __restrict__ repT)
{
    #pragma unroll 8
    for (int i = 0; i < 128; ++i) {
        const int ig = i0 + i;                 // uniform -> s_load path
        const float sxp = posP[3 * ig];
        const float syp = posP[3 * ig + 1];
        const float szp = posP[3 * ig + 2];
        const float sxt = posT[3 * ig];
        const float syt = posT[3 * ig + 1];
        const float szt = posT[3 * ig + 2];
        // uniform mask -> SALU compare/select (q8 weight 0 or 256)
        const unsigned ms = (mask[ig] != 0.0f) ? 256u : 0u;

        unsigned tot = ms & vj;                // vj per-lane 0 / ~0
        if (DIAG) tot = (iLoc0 + i < t) ? tot : 0u;   // i<j on diagonal tile
        const float wpf = (float)tot;

        // packed pred/true distance chains (v_pk_sub / v_pk_fma)
        const v2f dx = (v2f){sxp, sxt} - xj;
        const v2f dy = (v2f){syp, syt} - yj;
        const v2f dz = (v2f){szp, szt} - zj;
        v2f d2 = dx * dx;
        d2 = dy * dy + d2;
        d2 = dz * dz + d2;
        d2 = d2 * 4.0f;                        // t = d/0.5 -> sqrt(4*d2)

        // pred chain
        const float ttp = fminf(__builtin_amdgcn_sqrtf(d2.x), 200.0f);
        const unsigned lop = (unsigned)ttp;
        const unsigned qp  = (unsigned)fmaf(wpf, __builtin_amdgcn_fractf(ttp), 0.5f);
        atomicAdd(&repP[lop], (qp << 16) + (tot - qp));      // ds_add_u32

        // true chain (independent -> ILP)
        const float ttt = fminf(__builtin_amdgcn_sqrtf(d2.y), 200.0f);
        const unsigned lot = (unsigned)ttt;
        const unsigned qt  = (unsigned)fmaf(wpf, __builtin_amdgcn_fractf(ttt), 0.5f);
        atomicAdd(&repT[lot], (qt << 16) + (tot - qt));      // ds_add_u32
    }
}

__global__ __launch_bounds__(TILE) void saxs_hist_kernel(
    const float* __restrict__ posPred,
    const float* __restrict__ posTrue,
    const float* __restrict__ mask,
    unsigned long long* __restrict__ gh,
    unsigned int* __restrict__ counter,
    float* __restrict__ out)
{
    const int t = threadIdx.x;

    // Decode triangular tile index -> (a, b), a <= b. Wave-uniform, once.
    int p = blockIdx.x;
    int a = 0;
    while (p >= NTILES - a) { p -= NTILES - a; ++a; }
    const int b = a + p;

    __shared__ unsigned int sHist[2 * NREP * RSTRIDE];   // 25728 B -> 6 blocks/CU
    {   // vectorized zero-init (6432 u32 = 1608 uint4)
        uint4* s4 = (uint4*)sHist;
        for (int k = t; k < (2 * NREP * RSTRIDE) / 4; k += TILE)
            s4[k] = make_uint4(0u, 0u, 0u, 0u);
    }

    // j-atom (one per thread) from tile b, both structures (raw coords).
    const int jg = b * TILE + t;
    const v2f xj = (v2f){posPred[3 * jg],     posTrue[3 * jg]};
    const v2f yj = (v2f){posPred[3 * jg + 1], posTrue[3 * jg + 1]};
    const v2f zj = (v2f){posPred[3 * jg + 2], posTrue[3 * jg + 2]};
    const unsigned vj = (mask[jg] != 0.0f) ? 0xFFFFFFFFu : 0u;

    __syncthreads();

    unsigned int* __restrict__ repP = sHist + (t & (NREP - 1)) * RSTRIDE;
    unsigned int* __restrict__ repT = repP + SOFF;

    // This block handles 128 i-atoms: tile-local [128*by, 128*by+128).
    const int iLoc0 = 128 * blockIdx.y;
    const int i0 = __builtin_amdgcn_readfirstlane(a * TILE + iLoc0);

    if (a != b) accum_tile<false>(posPred, posTrue, mask, i0, iLoc0, t,
                                  xj, yj, zj, vj, repP, repT);
    else        accum_tile<true >(posPred, posTrue, mask, i0, iLoc0, t,
                                  xj, yj, zj, vj, repP, repT);

    __syncthreads();

    // Reduce replicas: bin k = sum_r low16(W[r][k]) + high16(W[r][k-1]);
    // both structures (402 bins total), one global u64 add per bin per block.
    for (int k = t; k < 2 * NBINS; k += TILE) {
        const int s  = (k < NBINS) ? 0 : 1;
        const int kk = k - s * NBINS;
        const unsigned int* h = sHist + s * SOFF;
        unsigned int acc = 0;
        #pragma unroll
        for (int r = 0; r < NREP; ++r) {
            acc += h[r * RSTRIDE + kk] & 0xFFFFu;
            if (kk > 0) acc += h[r * RSTRIDE + kk - 1] >> 16;
        }
        atomicAdd(&gh[s * HSTRIDE + kk], (unsigned long long)acc);
    }

    // ---- fused loss: last block to finish computes the L1 of normalized hists
    __syncthreads();
    __shared__ int sLast;
    if (t == 0) {
        __threadfence();                   // publish our adds (device scope)
        const unsigned prev = __hip_atomic_fetch_add(
            counter, 1u, __ATOMIC_ACQ_REL, __HIP_MEMORY_SCOPE_AGENT);
        sLast = (prev == 2u * TPAIRS - 1u);
    }
    __syncthreads();
    if (sLast && t < 64) {
        const int ln = t;                  // single wave of 64
        float hp[4], ht[4];
        float sp = 0.0f, st = 0.0f;
        #pragma unroll
        for (int r = 0; r < 4; ++r) {
            const int k = ln + 64 * r;
            float av = 0.0f, cv = 0.0f;
            if (k < NBINS) {
                av = (float)__hip_atomic_load(&gh[k],           __ATOMIC_RELAXED,
                                              __HIP_MEMORY_SCOPE_AGENT);
                cv = (float)__hip_atomic_load(&gh[HSTRIDE + k], __ATOMIC_RELAXED,
                                              __HIP_MEMORY_SCOPE_AGENT);
            }
            hp[r] = av; ht[r] = cv;
            sp += av; st += cv;
        }
        #pragma unroll
        for (int off = 32; off > 0; off >>= 1) {
            sp += __shfl_xor(sp, off);
            st += __shfl_xor(st, off);
        }
        sp += 1e-12f;
        st += 1e-12f;
        float l = 0.0f;
        #pragma unroll
        for (int r = 0; r < 4; ++r) l += fabsf(hp[r] / sp - ht[r] / st);
        #pragma unroll
        for (int off = 32; off > 0; off >>= 1) l += __shfl_xor(l, off);
        if (ln == 0) out[0] = l;
    }
}

extern "C" void kernel_launch(void* const* d_in, const int* in_sizes, int n_in,
                              void* d_out, int out_size, void* d_ws, size_t ws_size,
                              hipStream_t stream)
{
    const float* pred = (const float*)d_in[0];  // final_atom_positions [256,37,3]
    const float* tru  = (const float*)d_in[1];  // all_atom_positions   [256,37,3]
    const float* msk  = (const float*)d_in[2];  // all_atom_mask        [256,37]
    float* out = (float*)d_out;
    unsigned long long* ws = (unsigned long long*)d_ws;
    unsigned int* counter = (unsigned int*)(ws + 2 * HSTRIDE);

    // ws is poisoned 0xAA before every timed launch — zero hists + counter.
    hipMemsetAsync(d_ws, 0, (2 * HSTRIDE + 1) * sizeof(unsigned long long), stream);

    saxs_hist_kernel<<<dim3(TPAIRS, 2), dim3(TILE), 0, stream>>>(
        pred, tru, msk, ws, counter, out);
}